// Round 1
// baseline (4269.737 us; speedup 1.0000x reference)
//
#include <hip/hip_runtime.h>
#include <cmath>

// Problem constants
// B=2048, N=49, C=192, H=6, D=32
static constexpr float SCALE_ = 0.17677669529663687f; // 32^-0.5

// ---------------------------------------------------------------------------
// Small weight-combine GEMM: out[m,n] = scale * sum_k Wa[m,k]*Wb[k,n]
// Wa is 192x192, Wb is 192xNCb, out is 192xNCb.
// ---------------------------------------------------------------------------
__global__ __launch_bounds__(256) void smallmm_kernel(
    const float* __restrict__ Wa, const float* __restrict__ Wb,
    const float* __restrict__ scale_p, float* __restrict__ out, int NCb)
{
    int idx = blockIdx.x * 256 + threadIdx.x;
    int n4  = NCb >> 2;
    int m   = idx / n4;
    int n0  = (idx - m * n4) << 2;
    if (m >= 192) return;
    float s = scale_p[0];
    float ax = 0.f, ay = 0.f, az = 0.f, aw = 0.f;
    for (int k = 0; k < 192; ++k) {
        float a = Wa[m * 192 + k];
        const float4 b = *(const float4*)(Wb + (size_t)k * NCb + n0);
        ax += a * b.x; ay += a * b.y; az += a * b.z; aw += a * b.w;
    }
    float4 r = make_float4(ax * s, ay * s, az * s, aw * s);
    *(float4*)(out + (size_t)m * NCb + n0) = r;
}

// ---------------------------------------------------------------------------
// Fused dual-A GEMM:  out[m,:] = A1[m,:] @ W1 + A2[m,:] @ W2 + bias
// A rows are addressed as (bb = m/R, r = m%R): row ptr = A + bb*a_bs + r*192.
// K = 192 per operand. NC in {192,384,576}. Tile 64x64, thread 4x4.
// A2 may be nullptr (single-operand GEMM, e.g. output projection).
// ---------------------------------------------------------------------------
__global__ __launch_bounds__(256) void gemm2_kernel(
    const float* __restrict__ A1, long long a1_bs,
    const float* __restrict__ A2, long long a2_bs,
    const float* __restrict__ W1, const float* __restrict__ W2,
    const float* __restrict__ bias,
    float* __restrict__ out, long long out_bs,
    int R, int NC, int M)
{
    __shared__ __align__(16) float As[16][68];
    __shared__ __align__(16) float Ws[16][68];

    const int tid = threadIdx.x;
    const int bm = blockIdx.x, bn = blockIdx.y;
    const int tx = tid & 15, ty = tid >> 4;

    // A-tile load mapping: 64 rows x 16 k, each thread loads one float4 over k
    const int lr  = tid >> 2;          // 0..63 row in tile
    const int lk4 = (tid & 3) << 2;    // 0,4,8,12
    const int m_l = bm * 64 + lr;
    const float* a1row = nullptr;
    const float* a2row = nullptr;
    if (m_l < M) {
        int bb = m_l / R, r = m_l - bb * R;
        a1row = A1 + (long long)bb * a1_bs + (long long)r * 192;
        if (A2) a2row = A2 + (long long)bb * a2_bs + (long long)r * 192;
    }
    // W-tile load mapping: 16 k x 64 n, each thread loads one float4 over n
    const int wk  = tid >> 4;          // 0..15
    const int wn4 = (tid & 15) << 2;   // 0..60

    float acc[4][4] = {};
    const int nk = A2 ? 24 : 12;

    for (int kt = 0; kt < nk; ++kt) {
        const bool second = (kt >= 12);
        const int k0 = (second ? kt - 12 : kt) << 4;
        float4 av = make_float4(0.f, 0.f, 0.f, 0.f);
        const float* arow = second ? a2row : a1row;
        if (arow) av = *(const float4*)(arow + k0 + lk4);
        const float* Wp = second ? W2 : W1;
        const float4 wv = *(const float4*)(Wp + (size_t)(k0 + wk) * NC + bn * 64 + wn4);

        __syncthreads();
        As[lk4 + 0][lr] = av.x;
        As[lk4 + 1][lr] = av.y;
        As[lk4 + 2][lr] = av.z;
        As[lk4 + 3][lr] = av.w;
        *(float4*)&Ws[wk][wn4] = wv;
        __syncthreads();

        #pragma unroll
        for (int kk = 0; kk < 16; ++kk) {
            const float4 a4 = *(const float4*)&As[kk][ty << 2];
            const float4 w4 = *(const float4*)&Ws[kk][tx << 2];
            const float aa[4] = {a4.x, a4.y, a4.z, a4.w};
            const float ww[4] = {w4.x, w4.y, w4.z, w4.w};
            #pragma unroll
            for (int ii = 0; ii < 4; ++ii)
                #pragma unroll
                for (int jj = 0; jj < 4; ++jj)
                    acc[ii][jj] += aa[ii] * ww[jj];
        }
    }

    const int n0 = bn * 64 + (tx << 2);
    float4 bv = make_float4(0.f, 0.f, 0.f, 0.f);
    if (bias) bv = *(const float4*)(bias + n0);
    #pragma unroll
    for (int ii = 0; ii < 4; ++ii) {
        int m = bm * 64 + (ty << 2) + ii;
        if (m < M) {
            int bb = m / R, r = m - bb * R;
            float4 o;
            o.x = acc[ii][0] + bv.x;
            o.y = acc[ii][1] + bv.y;
            o.z = acc[ii][2] + bv.z;
            o.w = acc[ii][3] + bv.w;
            *(float4*)(out + (long long)bb * out_bs + (long long)r * NC + n0) = o;
        }
    }
}

// ---------------------------------------------------------------------------
// Differential attention for one (batch, head):
//   St = SCALE*qt@kt^T + bias ; Sr likewise ; softmax rows
//   ot = (at - lam*ar)@vt ; orf = (ar - lam*at)@vr
// All six operand tensors given as (base including column offset,
// batch stride, row stride); head column offset h*32 is added in-kernel.
// Outputs written merged: (cb*49, 192) at column h*32.
// ---------------------------------------------------------------------------
__global__ __launch_bounds__(256) void attn_kernel(
    const float* __restrict__ qT, long long qT_bs, int qT_rs,
    const float* __restrict__ kT, long long kT_bs, int kT_rs,
    const float* __restrict__ vT, long long vT_bs, int vT_rs,
    const float* __restrict__ qR, long long qR_bs, int qR_rs,
    const float* __restrict__ kR, long long kR_bs, int kR_rs,
    const float* __restrict__ vR, long long vR_bs, int vR_rs,
    const float* __restrict__ rpb, const float* __restrict__ lam_ptr,
    float* __restrict__ otm, float* __restrict__ orfm, long long o_bs)
{
    // inner dim padded to 33 (bank-conflict-free column access),
    // rows padded to 52 (guard-free 4x4 tiling over 49)
    __shared__ float qs[2][52][33];
    __shared__ float ks[2][52][33];
    __shared__ float vs[2][52][33];
    __shared__ float Ps[2][52][53];
    __shared__ float bias_h[170];

    const int tid = threadIdx.x;
    const int bb = blockIdx.x / 6;
    const int h  = blockIdx.x - bb * 6;
    const int hoff = h * 32;

    for (int idx = tid; idx < 52 * 32; idx += 256) {
        int n = idx >> 5, d = idx & 31;
        bool ok = (n < 49);
        qs[0][n][d] = ok ? qT[(long long)bb * qT_bs + (long long)n * qT_rs + hoff + d] : 0.f;
        qs[1][n][d] = ok ? qR[(long long)bb * qR_bs + (long long)n * qR_rs + hoff + d] : 0.f;
        ks[0][n][d] = ok ? kT[(long long)bb * kT_bs + (long long)n * kT_rs + hoff + d] : 0.f;
        ks[1][n][d] = ok ? kR[(long long)bb * kR_bs + (long long)n * kR_rs + hoff + d] : 0.f;
        vs[0][n][d] = ok ? vT[(long long)bb * vT_bs + (long long)n * vT_rs + hoff + d] : 0.f;
        vs[1][n][d] = ok ? vR[(long long)bb * vR_bs + (long long)n * vR_rs + hoff + d] : 0.f;
    }
    for (int idx = tid; idx < 169; idx += 256) bias_h[idx] = rpb[idx * 6 + h];

    float lraw = lam_ptr[0];
    float lam = 1.f / (1.f + expf(-lraw));
    lam = fminf(fmaxf(lam, 0.01f), 0.99f);
    __syncthreads();

    // ---- scores: 2 streams x 13x13 tiles of 4x4 ----
    for (int task = tid; task < 338; task += 256) {
        int s = task / 169;
        int rem = task - s * 169;
        int it = rem / 13, jt = rem - it * 13;
        int i0 = it * 4, j0 = jt * 4;
        float acc[4][4] = {};
        for (int d = 0; d < 32; ++d) {
            float qv[4], kv[4];
            #pragma unroll
            for (int ii = 0; ii < 4; ++ii) qv[ii] = qs[s][i0 + ii][d];
            #pragma unroll
            for (int jj = 0; jj < 4; ++jj) kv[jj] = ks[s][j0 + jj][d];
            #pragma unroll
            for (int ii = 0; ii < 4; ++ii)
                #pragma unroll
                for (int jj = 0; jj < 4; ++jj)
                    acc[ii][jj] += qv[ii] * kv[jj];
        }
        #pragma unroll
        for (int ii = 0; ii < 4; ++ii) {
            #pragma unroll
            for (int jj = 0; jj < 4; ++jj) {
                int i = i0 + ii, j = j0 + jj;
                int ic = (i < 49) ? i : 48;
                int jc = (j < 49) ? j : 48;
                int ri = ic / 7, rj = jc / 7;
                int dr = ri - rj + 6;
                int dc = (ic - ri * 7) - (jc - rj * 7) + 6;
                Ps[s][i][j] = acc[ii][jj] * SCALE_ + bias_h[dr * 13 + dc];
            }
        }
    }
    __syncthreads();

    // ---- softmax per row (98 rows total across both streams) ----
    if (tid < 98) {
        int s = tid / 49, i = tid - s * 49;
        float mx = -1e30f;
        for (int j = 0; j < 49; ++j) mx = fmaxf(mx, Ps[s][i][j]);
        float sum = 0.f;
        for (int j = 0; j < 49; ++j) {
            float e = expf(Ps[s][i][j] - mx);
            Ps[s][i][j] = e;
            sum += e;
        }
        float inv = 1.f / sum;
        for (int j = 0; j < 49; ++j) Ps[s][i][j] *= inv;
    }
    __syncthreads();

    // ---- PV: 2 streams x 13 i-tiles x 8 d-tiles of 4x4 ----
    for (int task = tid; task < 208; task += 256) {
        int s = task / 104;
        int rem = task - s * 104;
        int it = rem / 8, dt = rem - it * 8;
        int i0 = it * 4, d0 = dt * 4;
        float acc[4][4] = {};
        for (int j = 0; j < 49; ++j) {
            float c[4], vv[4];
            #pragma unroll
            for (int ii = 0; ii < 4; ++ii) {
                float pt = Ps[0][i0 + ii][j];
                float pr = Ps[1][i0 + ii][j];
                c[ii] = (s == 0) ? (pt - lam * pr) : (pr - lam * pt);
            }
            #pragma unroll
            for (int dd = 0; dd < 4; ++dd) vv[dd] = vs[s][j][d0 + dd];
            #pragma unroll
            for (int ii = 0; ii < 4; ++ii)
                #pragma unroll
                for (int dd = 0; dd < 4; ++dd)
                    acc[ii][dd] += c[ii] * vv[dd];
        }
        float* op = (s == 0) ? otm : orfm;
        #pragma unroll
        for (int ii = 0; ii < 4; ++ii) {
            int i = i0 + ii;
            if (i < 49) {
                float4 o = make_float4(acc[ii][0], acc[ii][1], acc[ii][2], acc[ii][3]);
                *(float4*)(op + (long long)bb * o_bs + (long long)i * 192 + hoff + d0) = o;
            }
        }
    }
}

// ---------------------------------------------------------------------------
extern "C" void kernel_launch(void* const* d_in, const int* in_sizes, int n_in,
                              void* d_out, int out_size, void* d_ws, size_t ws_size,
                              hipStream_t stream)
{
    const float* x_sa      = (const float*)d_in[0];
    const float* x_ca      = (const float*)d_in[1];
    const float* lam_sa    = (const float*)d_in[2];
    const float* lam_ca    = (const float*)d_in[3];
    const float* sa_enh    = (const float*)d_in[4];
    const float* ca_enh    = (const float*)d_in[5];
    const float* W_sa_qkv  = (const float*)d_in[6];
    const float* b_sa_qkv  = (const float*)d_in[7];
    const float* W_sa_ct   = (const float*)d_in[8];
    const float* W_sa_cr   = (const float*)d_in[9];
    const float* W_ca_q    = (const float*)d_in[10];
    const float* b_ca_q    = (const float*)d_in[11];
    const float* W_ca_kv   = (const float*)d_in[12];
    const float* b_ca_kv   = (const float*)d_in[13];
    const float* W_ca_ct   = (const float*)d_in[14];
    const float* W_ca_cr   = (const float*)d_in[15];
    const float* rpb       = (const float*)d_in[16];
    const float* W_proj_sa = (const float*)d_in[17];
    const float* b_proj_sa = (const float*)d_in[18];
    const float* W_proj_ca = (const float*)d_in[19];
    const float* b_proj_ca = (const float*)d_in[20];
    float* out = (float*)d_out;
    float* ws  = (float*)d_ws;

    // ---- combined weights (fold the "enhance" GEMM into downstream GEMMs) ----
    float* CW0 = ws;             // sa_enh * W_sa_cr @ W_sa_qkv   (192x576)
    float* CW1 = CW0 + 110592;   // sa_enh * W_sa_ct @ W_sa_qkv   (192x576)
    float* CW2 = CW1 + 110592;   // ca_enh * W_ca_cr @ W_ca_q     (192x192)
    float* CW3 = CW2 + 36864;    // ca_enh * W_ca_ct @ W_ca_q     (192x192)
    float* CW4 = CW3 + 36864;    // ca_enh * W_ca_cr @ W_ca_kv    (192x384)
    float* CW5 = CW4 + 73728;    // ca_enh * W_ca_ct @ W_ca_kv    (192x384)
    float* chunkbuf = CW5 + 73728;  // = ws + 442368 floats

    smallmm_kernel<<<108, 256, 0, stream>>>(W_sa_cr, W_sa_qkv, sa_enh, CW0, 576);
    smallmm_kernel<<<108, 256, 0, stream>>>(W_sa_ct, W_sa_qkv, sa_enh, CW1, 576);
    smallmm_kernel<<< 36, 256, 0, stream>>>(W_ca_cr, W_ca_q,   ca_enh, CW2, 192);
    smallmm_kernel<<< 36, 256, 0, stream>>>(W_ca_ct, W_ca_q,   ca_enh, CW3, 192);
    smallmm_kernel<<< 72, 256, 0, stream>>>(W_ca_cr, W_ca_kv,  ca_enh, CW4, 384);
    smallmm_kernel<<< 72, 256, 0, stream>>>(W_ca_ct, W_ca_kv,  ca_enh, CW5, 384);

    // per-batch chunk workspace need: 75264 floats (SA and CA identical)
    long long avail = (long long)(ws_size / 4) - 442368;
    int cbmax = (int)(avail / 75264);
    if (cbmax > 2048) cbmax = 2048;
    if (cbmax < 1) cbmax = 1;

    const long long OUT1 = 2LL * 2048 * 49 * 192;  // start of out[1]
    dim3 blk(256);

    for (int c0 = 0; c0 < 2048; c0 += cbmax) {
        int cb = (c0 + cbmax <= 2048) ? cbmax : (2048 - c0);
        int M = cb * 49;
        int gx = (M + 63) / 64;

        // =========================== SA branch ===========================
        float* qkvt = chunkbuf;
        float* qkvr = qkvt + (long long)cbmax * 28224;
        float* otb  = qkvr + (long long)cbmax * 28224;
        float* orfb = otb  + (long long)cbmax * 9408;

        dim3 g1(gx, 9);
        // qkv_t = xt @ Wqkv + xr @ CW0 + b
        gemm2_kernel<<<g1, blk, 0, stream>>>(
            x_sa + (long long)c0 * 9408, 9408,
            x_sa + (2048LL + c0) * 9408, 9408,
            W_sa_qkv, CW0, b_sa_qkv, qkvt, 28224, 49, 576, M);
        // qkv_r = xr @ Wqkv + xt @ CW1 + b
        gemm2_kernel<<<g1, blk, 0, stream>>>(
            x_sa + (2048LL + c0) * 9408, 9408,
            x_sa + (long long)c0 * 9408, 9408,
            W_sa_qkv, CW1, b_sa_qkv, qkvr, 28224, 49, 576, M);

        attn_kernel<<<cb * 6, blk, 0, stream>>>(
            qkvt,       28224, 576,  qkvt + 192, 28224, 576,  qkvt + 384, 28224, 576,
            qkvr,       28224, 576,  qkvr + 192, 28224, 576,  qkvr + 384, 28224, 576,
            rpb, lam_sa, otb, orfb, 9408);

        dim3 g2(gx, 3);
        gemm2_kernel<<<g2, blk, 0, stream>>>(
            otb, 9408, nullptr, 0, W_proj_sa, nullptr, b_proj_sa,
            out + (long long)c0 * 9408, 9408, 49, 192, M);
        gemm2_kernel<<<g2, blk, 0, stream>>>(
            orfb, 9408, nullptr, 0, W_proj_sa, nullptr, b_proj_sa,
            out + (2048LL + c0) * 9408, 9408, 49, 192, M);

        // =========================== CA branch ===========================
        float* q_t  = chunkbuf;
        float* q_r  = q_t  + (long long)cbmax * 9408;
        float* kv_t = q_r  + (long long)cbmax * 9408;
        float* kv_r = kv_t + (long long)cbmax * 18816;
        float* otc  = kv_r + (long long)cbmax * 18816;
        float* orfc = otc  + (long long)cbmax * 9408;

        const float* xt_ca = x_ca + (long long)c0 * 18816;
        const float* xr_ca = xt_ca + 9408;

        // q_t = xt @ Wq + xr @ CW2 + b ; q_r = xr @ Wq + xt @ CW3 + b
        gemm2_kernel<<<g2, blk, 0, stream>>>(
            xt_ca, 18816, xr_ca, 18816, W_ca_q, CW2, b_ca_q, q_t, 9408, 49, 192, M);
        gemm2_kernel<<<g2, blk, 0, stream>>>(
            xr_ca, 18816, xt_ca, 18816, W_ca_q, CW3, b_ca_q, q_r, 9408, 49, 192, M);

        dim3 g3(gx, 6);
        // kv_t = xt @ Wkv + xr @ CW4 + b ; kv_r = xr @ Wkv + xt @ CW5 + b
        gemm2_kernel<<<g3, blk, 0, stream>>>(
            xt_ca, 18816, xr_ca, 18816, W_ca_kv, CW4, b_ca_kv, kv_t, 18816, 49, 384, M);
        gemm2_kernel<<<g3, blk, 0, stream>>>(
            xr_ca, 18816, xt_ca, 18816, W_ca_kv, CW5, b_ca_kv, kv_r, 18816, 49, 384, M);

        attn_kernel<<<cb * 6, blk, 0, stream>>>(
            q_t,  9408, 192,  kv_t,       18816, 384,  kv_t + 192, 18816, 384,
            q_r,  9408, 192,  kv_r,       18816, 384,  kv_r + 192, 18816, 384,
            rpb, lam_ca, otc, orfc, 9408);

        gemm2_kernel<<<g2, blk, 0, stream>>>(
            otc, 9408, nullptr, 0, W_proj_ca, nullptr, b_proj_ca,
            out + OUT1 + (long long)c0 * 18816, 18816, 49, 192, M);
        gemm2_kernel<<<g2, blk, 0, stream>>>(
            orfc, 9408, nullptr, 0, W_proj_ca, nullptr, b_proj_ca,
            out + OUT1 + (long long)c0 * 18816 + 9408, 18816, 49, 192, M);
    }
}

// Round 2
// 2876.012 us; speedup vs baseline: 1.4846x; 1.4846x over previous
//
#include <hip/hip_runtime.h>
#include <cmath>

static constexpr float SCALE_ = 0.17677669529663687f; // 32^-0.5

typedef __attribute__((ext_vector_type(8))) short bf16x8;
typedef __attribute__((ext_vector_type(4))) float f32x4;

__device__ inline ushort bf16h(float f) {
    uint x = __float_as_uint(f);
    return (ushort)((x + 0x7fffu + ((x >> 16) & 1u)) >> 16);
}
__device__ inline float bf16f(ushort u) {
    return __uint_as_float(((uint)u) << 16);
}

// ---------------------------------------------------------------------------
// Small weight-combine GEMM: out[m,n] = scale * sum_k Wa[m,k]*Wb[k,n]
// ---------------------------------------------------------------------------
__global__ __launch_bounds__(256) void smallmm_kernel(
    const float* __restrict__ Wa, const float* __restrict__ Wb,
    const float* __restrict__ scale_p, float* __restrict__ out, int NCb)
{
    int idx = blockIdx.x * 256 + threadIdx.x;
    int n4  = NCb >> 2;
    int m   = idx / n4;
    int n0  = (idx - m * n4) << 2;
    if (m >= 192) return;
    float s = scale_p[0];
    float ax = 0.f, ay = 0.f, az = 0.f, aw = 0.f;
    for (int k = 0; k < 192; ++k) {
        float a = Wa[m * 192 + k];
        const float4 b = *(const float4*)(Wb + (size_t)k * NCb + n0);
        ax += a * b.x; ay += a * b.y; az += a * b.z; aw += a * b.w;
    }
    float4 r = make_float4(ax * s, ay * s, az * s, aw * s);
    *(float4*)(out + (size_t)m * NCb + n0) = r;
}

// ---------------------------------------------------------------------------
// Split-bf16 MFMA GEMM: out = A1@W1 [+ A2@W2] + bias.
// fp32 operands split to bf16 hi/lo; D = Ah@Bh + Ah@Bl + Al@Bh (3 MFMAs),
// rel error ~2^-16. Block tile 128x64, 4 waves of 64x32, 16x16x32 MFMA,
// BK=32. A rows addressed as (bb=m/49, r=m%49). R==49 hardcoded.
// ---------------------------------------------------------------------------
__global__ __launch_bounds__(256) void gemm_mfma(
    const float* __restrict__ A1, long long a1_bs,
    const float* __restrict__ A2, long long a2_bs,
    const float* __restrict__ W1, const float* __restrict__ W2,
    const float* __restrict__ bias,
    float* __restrict__ out, long long out_bs,
    int NC, int M)
{
    // [row][k] bf16, row pad 40 (80B, 16B-aligned, uniform-slot b128 reads)
    __shared__ __align__(16) ushort Ah[128][40];
    __shared__ __align__(16) ushort Al[128][40];
    __shared__ __align__(16) ushort Bh[64][40];   // [n][k] (transposed W)
    __shared__ __align__(16) ushort Bl[64][40];

    const int tid = threadIdx.x;
    const int bm = blockIdx.x, bn = blockIdx.y;

    // A staging map: thread -> (row 0..127, k-half 0/16), 4 float4 each
    const int ar  = tid >> 1;
    const int ak0 = (tid & 1) << 4;
    int m_l = bm * 128 + ar;
    if (m_l >= M) m_l = M - 1;
    const int abb = m_l / 49, arr = m_l - abb * 49;
    const float* a1p = A1 + (long long)abb * a1_bs + arr * 192 + ak0;
    const float* a2p = A2 ? (A2 + (long long)abb * a2_bs + arr * 192 + ak0) : nullptr;

    // W staging map: thread -> (k 0..31, two f4 cols)
    const int wk = tid >> 3;
    const int wf = tid & 7;

    const int lane = tid & 63;
    const int wv = tid >> 6;
    const int wm = (wv >> 1) << 6;   // 0 / 64
    const int wn = (wv & 1) << 5;    // 0 / 32
    const int lr = lane & 15;
    const int lg = lane >> 4;

    f32x4 acc[4][2] = {};

    const int nslab = A2 ? 12 : 6;
    for (int slab = 0; slab < nslab; ++slab) {
        const int k6 = (slab < 6) ? slab : slab - 6;
        const float* ap = (slab < 6) ? a1p : a2p;
        const float* Wp = (slab < 6) ? W1 : W2;

        float4 av[4];
        #pragma unroll
        for (int i = 0; i < 4; ++i)
            av[i] = *(const float4*)(ap + k6 * 32 + 4 * i);
        const float* wrow = Wp + (size_t)(k6 * 32 + wk) * NC + bn * 64;
        float4 wv0 = *(const float4*)(wrow + wf * 4);
        float4 wv1 = *(const float4*)(wrow + (wf + 8) * 4);

        __syncthreads();   // previous slab's frag reads complete
        #pragma unroll
        for (int i = 0; i < 4; ++i) {
            float fs[4] = {av[i].x, av[i].y, av[i].z, av[i].w};
            ushort4 hq, lq;
            ushort* hp = (ushort*)&hq; ushort* lp = (ushort*)&lq;
            #pragma unroll
            for (int e = 0; e < 4; ++e) {
                ushort hh = bf16h(fs[e]);
                hp[e] = hh;
                lp[e] = bf16h(fs[e] - bf16f(hh));
            }
            *(ushort4*)&Ah[ar][ak0 + 4 * i] = hq;
            *(ushort4*)&Al[ar][ak0 + 4 * i] = lq;
        }
        {
            float f0[4] = {wv0.x, wv0.y, wv0.z, wv0.w};
            float f1[4] = {wv1.x, wv1.y, wv1.z, wv1.w};
            #pragma unroll
            for (int e = 0; e < 4; ++e) {
                int n0 = wf * 4 + e;
                ushort hh = bf16h(f0[e]);
                Bh[n0][wk] = hh;
                Bl[n0][wk] = bf16h(f0[e] - bf16f(hh));
                int n1 = (wf + 8) * 4 + e;
                ushort h2 = bf16h(f1[e]);
                Bh[n1][wk] = h2;
                Bl[n1][wk] = bf16h(f1[e] - bf16f(h2));
            }
        }
        __syncthreads();

        bf16x8 fah[4], fal[4], fbh[2], fbl[2];
        #pragma unroll
        for (int i = 0; i < 4; ++i) {
            fah[i] = *(const bf16x8*)&Ah[wm + 16 * i + lr][8 * lg];
            fal[i] = *(const bf16x8*)&Al[wm + 16 * i + lr][8 * lg];
        }
        #pragma unroll
        for (int j = 0; j < 2; ++j) {
            fbh[j] = *(const bf16x8*)&Bh[wn + 16 * j + lr][8 * lg];
            fbl[j] = *(const bf16x8*)&Bl[wn + 16 * j + lr][8 * lg];
        }
        #pragma unroll
        for (int i = 0; i < 4; ++i)
            #pragma unroll
            for (int j = 0; j < 2; ++j) {
                acc[i][j] = __builtin_amdgcn_mfma_f32_16x16x32_bf16(fah[i], fbh[j], acc[i][j], 0, 0, 0);
                acc[i][j] = __builtin_amdgcn_mfma_f32_16x16x32_bf16(fah[i], fbl[j], acc[i][j], 0, 0, 0);
                acc[i][j] = __builtin_amdgcn_mfma_f32_16x16x32_bf16(fal[i], fbh[j], acc[i][j], 0, 0, 0);
            }
    }

    // epilogue: C/D layout col=lane&15, row=4*(lane>>4)+reg
    #pragma unroll
    for (int j = 0; j < 2; ++j) {
        const int col = bn * 64 + wn + 16 * j + lr;
        const float bv = bias ? bias[col] : 0.f;
        #pragma unroll
        for (int i = 0; i < 4; ++i) {
            #pragma unroll
            for (int r = 0; r < 4; ++r) {
                int m = bm * 128 + wm + 16 * i + 4 * lg + r;
                if (m < M) {
                    int b2 = m / 49, r2 = m - b2 * 49;
                    out[(long long)b2 * out_bs + (long long)r2 * NC + col] = acc[i][j][r] + bv;
                }
            }
        }
    }
}

// ---------------------------------------------------------------------------
// Differential attention for one (batch, head).
// LDS-lean: K (both streams) staged in LDS; q read from global (L1/L2-hot);
// V re-staged into the K buffer after the score phase.
// ---------------------------------------------------------------------------
__global__ __launch_bounds__(256) void attn_kernel(
    const float* __restrict__ qT, long long qT_bs, int qT_rs,
    const float* __restrict__ kT, long long kT_bs, int kT_rs,
    const float* __restrict__ vT, long long vT_bs, int vT_rs,
    const float* __restrict__ qR, long long qR_bs, int qR_rs,
    const float* __restrict__ kR, long long kR_bs, int kR_rs,
    const float* __restrict__ vR, long long vR_bs, int vR_rs,
    const float* __restrict__ rpb, const float* __restrict__ lam_ptr,
    float* __restrict__ otm, float* __restrict__ orfm, long long o_bs)
{
    __shared__ float ksh[2][49][33];   // K, then reused for V
    __shared__ float Ps[2][52][53];
    __shared__ float bias_h[169];

    const int tid = threadIdx.x;
    const int bb = blockIdx.x / 6;
    const int h  = blockIdx.x - bb * 6;
    const int hoff = h * 32;

    // stage K (both streams): 2*49*32 = 3136 elems
    for (int idx = tid; idx < 3136; idx += 256) {
        int s = (idx >= 1568) ? 1 : 0;
        int rem = idx - s * 1568;
        int n = rem >> 5, d = rem & 31;
        const float* kp = s ? (kR + (long long)bb * kR_bs + hoff)
                            : (kT + (long long)bb * kT_bs + hoff);
        int rs = s ? kR_rs : kT_rs;
        ksh[s][n][d] = kp[(long long)n * rs + d];
    }
    for (int idx = tid; idx < 169; idx += 256) bias_h[idx] = rpb[idx * 6 + h];

    float lraw = lam_ptr[0];
    float lam = 1.f / (1.f + expf(-lraw));
    lam = fminf(fmaxf(lam, 0.01f), 0.99f);
    __syncthreads();

    // ---- scores: 2 streams x 13x13 tiles of 4x4; q from global ----
    for (int task = tid; task < 338; task += 256) {
        int s = (task >= 169) ? 1 : 0;
        int rem = task - s * 169;
        int it = rem / 13, jt = rem - it * 13;
        int i0 = it * 4, j0 = jt * 4;

        const float* qb = s ? (qR + (long long)bb * qR_bs + hoff)
                            : (qT + (long long)bb * qT_bs + hoff);
        const int qrs = s ? qR_rs : qT_rs;
        const float* qrow[4];
        int jr[4];
        #pragma unroll
        for (int ii = 0; ii < 4; ++ii) {
            int i = i0 + ii; if (i > 48) i = 48;
            qrow[ii] = qb + (long long)i * qrs;
            int j = j0 + ii; if (j > 48) j = 48;
            jr[ii] = j;
        }
        float acc[4][4] = {};
        #pragma unroll
        for (int dq = 0; dq < 8; ++dq) {
            float4 q4[4];
            #pragma unroll
            for (int ii = 0; ii < 4; ++ii)
                q4[ii] = *(const float4*)(qrow[ii] + dq * 4);
            float kvv[4][4];
            #pragma unroll
            for (int jj = 0; jj < 4; ++jj)
                #pragma unroll
                for (int dd = 0; dd < 4; ++dd)
                    kvv[jj][dd] = ksh[s][jr[jj]][dq * 4 + dd];
            #pragma unroll
            for (int ii = 0; ii < 4; ++ii)
                #pragma unroll
                for (int jj = 0; jj < 4; ++jj)
                    acc[ii][jj] += q4[ii].x * kvv[jj][0] + q4[ii].y * kvv[jj][1]
                                 + q4[ii].z * kvv[jj][2] + q4[ii].w * kvv[jj][3];
        }
        #pragma unroll
        for (int ii = 0; ii < 4; ++ii) {
            #pragma unroll
            for (int jj = 0; jj < 4; ++jj) {
                int i = i0 + ii, j = j0 + jj;
                int ic = (i < 49) ? i : 48;
                int jc = (j < 49) ? j : 48;
                int ri = ic / 7, rj = jc / 7;
                int dr = ri - rj + 6;
                int dc = (ic - ri * 7) - (jc - rj * 7) + 6;
                Ps[s][i][j] = acc[ii][jj] * SCALE_ + bias_h[dr * 13 + dc];
            }
        }
    }
    __syncthreads();

    // ---- stage V into ksh (K is dead) + softmax on Ps ----
    for (int idx = tid; idx < 3136; idx += 256) {
        int s = (idx >= 1568) ? 1 : 0;
        int rem = idx - s * 1568;
        int n = rem >> 5, d = rem & 31;
        const float* vp = s ? (vR + (long long)bb * vR_bs + hoff)
                            : (vT + (long long)bb * vT_bs + hoff);
        int rs = s ? vR_rs : vT_rs;
        ksh[s][n][d] = vp[(long long)n * rs + d];
    }
    if (tid < 98) {
        int s = tid / 49, i = tid - s * 49;
        float mx = -1e30f;
        for (int j = 0; j < 49; ++j) mx = fmaxf(mx, Ps[s][i][j]);
        float sum = 0.f;
        for (int j = 0; j < 49; ++j) {
            float e = expf(Ps[s][i][j] - mx);
            Ps[s][i][j] = e;
            sum += e;
        }
        float inv = 1.f / sum;
        for (int j = 0; j < 49; ++j) Ps[s][i][j] *= inv;
    }
    __syncthreads();

    // ---- PV: 2 streams x 13 i-tiles x 8 d-tiles of 4x4 ----
    for (int task = tid; task < 208; task += 256) {
        int s = task / 104;
        int rem = task - s * 104;
        int it = rem / 8, dt = rem - it * 8;
        int i0 = it * 4, d0 = dt * 4;
        float acc[4][4] = {};
        for (int j = 0; j < 49; ++j) {
            float c[4], vv[4];
            #pragma unroll
            for (int ii = 0; ii < 4; ++ii) {
                float pt = Ps[0][i0 + ii][j];
                float pr = Ps[1][i0 + ii][j];
                c[ii] = (s == 0) ? (pt - lam * pr) : (pr - lam * pt);
            }
            #pragma unroll
            for (int dd = 0; dd < 4; ++dd) vv[dd] = ksh[s][j][d0 + dd];
            #pragma unroll
            for (int ii = 0; ii < 4; ++ii)
                #pragma unroll
                for (int dd = 0; dd < 4; ++dd)
                    acc[ii][dd] += c[ii] * vv[dd];
        }
        float* op = (s == 0) ? otm : orfm;
        #pragma unroll
        for (int ii = 0; ii < 4; ++ii) {
            int i = i0 + ii;
            if (i < 49) {
                float4 o = make_float4(acc[ii][0], acc[ii][1], acc[ii][2], acc[ii][3]);
                *(float4*)(op + (long long)bb * o_bs + (long long)i * 192 + hoff + d0) = o;
            }
        }
    }
}

// ---------------------------------------------------------------------------
extern "C" void kernel_launch(void* const* d_in, const int* in_sizes, int n_in,
                              void* d_out, int out_size, void* d_ws, size_t ws_size,
                              hipStream_t stream)
{
    const float* x_sa      = (const float*)d_in[0];
    const float* x_ca      = (const float*)d_in[1];
    const float* lam_sa    = (const float*)d_in[2];
    const float* lam_ca    = (const float*)d_in[3];
    const float* sa_enh    = (const float*)d_in[4];
    const float* ca_enh    = (const float*)d_in[5];
    const float* W_sa_qkv  = (const float*)d_in[6];
    const float* b_sa_qkv  = (const float*)d_in[7];
    const float* W_sa_ct   = (const float*)d_in[8];
    const float* W_sa_cr   = (const float*)d_in[9];
    const float* W_ca_q    = (const float*)d_in[10];
    const float* b_ca_q    = (const float*)d_in[11];
    const float* W_ca_kv   = (const float*)d_in[12];
    const float* b_ca_kv   = (const float*)d_in[13];
    const float* W_ca_ct   = (const float*)d_in[14];
    const float* W_ca_cr   = (const float*)d_in[15];
    const float* rpb       = (const float*)d_in[16];
    const float* W_proj_sa = (const float*)d_in[17];
    const float* b_proj_sa = (const float*)d_in[18];
    const float* W_proj_ca = (const float*)d_in[19];
    const float* b_proj_ca = (const float*)d_in[20];
    float* out = (float*)d_out;
    float* ws  = (float*)d_ws;

    // ---- combined weights (fold the "enhance" GEMM into downstream GEMMs) ----
    float* CW0 = ws;             // sa_enh * W_sa_cr @ W_sa_qkv   (192x576)
    float* CW1 = CW0 + 110592;   // sa_enh * W_sa_ct @ W_sa_qkv   (192x576)
    float* CW2 = CW1 + 110592;   // ca_enh * W_ca_cr @ W_ca_q     (192x192)
    float* CW3 = CW2 + 36864;    // ca_enh * W_ca_ct @ W_ca_q     (192x192)
    float* CW4 = CW3 + 36864;    // ca_enh * W_ca_cr @ W_ca_kv    (192x384)
    float* CW5 = CW4 + 73728;    // ca_enh * W_ca_ct @ W_ca_kv    (192x384)
    float* chunkbuf = CW5 + 73728;  // = ws + 442368 floats

    smallmm_kernel<<<108, 256, 0, stream>>>(W_sa_cr, W_sa_qkv, sa_enh, CW0, 576);
    smallmm_kernel<<<108, 256, 0, stream>>>(W_sa_ct, W_sa_qkv, sa_enh, CW1, 576);
    smallmm_kernel<<< 36, 256, 0, stream>>>(W_ca_cr, W_ca_q,   ca_enh, CW2, 192);
    smallmm_kernel<<< 36, 256, 0, stream>>>(W_ca_ct, W_ca_q,   ca_enh, CW3, 192);
    smallmm_kernel<<< 72, 256, 0, stream>>>(W_ca_cr, W_ca_kv,  ca_enh, CW4, 384);
    smallmm_kernel<<< 72, 256, 0, stream>>>(W_ca_ct, W_ca_kv,  ca_enh, CW5, 384);

    long long avail = (long long)(ws_size / 4) - 442368;
    int cbmax = (int)(avail / 75264);
    if (cbmax > 2048) cbmax = 2048;
    if (cbmax < 1) cbmax = 1;

    const long long OUT1 = 2LL * 2048 * 49 * 192;
    dim3 blk(256);

    for (int c0 = 0; c0 < 2048; c0 += cbmax) {
        int cb = (c0 + cbmax <= 2048) ? cbmax : (2048 - c0);
        int M = cb * 49;
        int gx = (M + 127) / 128;

        // =========================== SA branch ===========================
        float* qkvt = chunkbuf;
        float* qkvr = qkvt + (long long)cbmax * 28224;
        float* otb  = qkvr + (long long)cbmax * 28224;
        float* orfb = otb  + (long long)cbmax * 9408;

        dim3 g1(gx, 9);
        gemm_mfma<<<g1, blk, 0, stream>>>(
            x_sa + (long long)c0 * 9408, 9408,
            x_sa + (2048LL + c0) * 9408, 9408,
            W_sa_qkv, CW0, b_sa_qkv, qkvt, 28224, 576, M);
        gemm_mfma<<<g1, blk, 0, stream>>>(
            x_sa + (2048LL + c0) * 9408, 9408,
            x_sa + (long long)c0 * 9408, 9408,
            W_sa_qkv, CW1, b_sa_qkv, qkvr, 28224, 576, M);

        attn_kernel<<<cb * 6, blk, 0, stream>>>(
            qkvt,       28224, 576,  qkvt + 192, 28224, 576,  qkvt + 384, 28224, 576,
            qkvr,       28224, 576,  qkvr + 192, 28224, 576,  qkvr + 384, 28224, 576,
            rpb, lam_sa, otb, orfb, 9408);

        dim3 g2(gx, 3);
        gemm_mfma<<<g2, blk, 0, stream>>>(
            otb, 9408, nullptr, 0, W_proj_sa, nullptr, b_proj_sa,
            out + (long long)c0 * 9408, 9408, 192, M);
        gemm_mfma<<<g2, blk, 0, stream>>>(
            orfb, 9408, nullptr, 0, W_proj_sa, nullptr, b_proj_sa,
            out + (2048LL + c0) * 9408, 9408, 192, M);

        // =========================== CA branch ===========================
        float* q_t  = chunkbuf;
        float* q_r  = q_t  + (long long)cbmax * 9408;
        float* kv_t = q_r  + (long long)cbmax * 9408;
        float* kv_r = kv_t + (long long)cbmax * 18816;
        float* otc  = kv_r + (long long)cbmax * 18816;
        float* orfc = otc  + (long long)cbmax * 9408;

        const float* xt_ca = x_ca + (long long)c0 * 18816;
        const float* xr_ca = xt_ca + 9408;

        gemm_mfma<<<g2, blk, 0, stream>>>(
            xt_ca, 18816, xr_ca, 18816, W_ca_q, CW2, b_ca_q, q_t, 9408, 192, M);
        gemm_mfma<<<g2, blk, 0, stream>>>(
            xr_ca, 18816, xt_ca, 18816, W_ca_q, CW3, b_ca_q, q_r, 9408, 192, M);

        dim3 g3(gx, 6);
        gemm_mfma<<<g3, blk, 0, stream>>>(
            xt_ca, 18816, xr_ca, 18816, W_ca_kv, CW4, b_ca_kv, kv_t, 18816, 384, M);
        gemm_mfma<<<g3, blk, 0, stream>>>(
            xr_ca, 18816, xt_ca, 18816, W_ca_kv, CW5, b_ca_kv, kv_r, 18816, 384, M);

        attn_kernel<<<cb * 6, blk, 0, stream>>>(
            q_t,  9408, 192,  kv_t,       18816, 384,  kv_t + 192, 18816, 384,
            q_r,  9408, 192,  kv_r,       18816, 384,  kv_r + 192, 18816, 384,
            rpb, lam_ca, otc, orfc, 9408);

        gemm_mfma<<<g2, blk, 0, stream>>>(
            otc, 9408, nullptr, 0, W_proj_ca, nullptr, b_proj_ca,
            out + OUT1 + (long long)c0 * 18816, 18816, 192, M);
        gemm_mfma<<<g2, blk, 0, stream>>>(
            orfc, 9408, nullptr, 0, W_proj_ca, nullptr, b_proj_ca,
            out + OUT1 + (long long)c0 * 18816 + 9408, 18816, 192, M);
    }
}

// Round 3
// 1765.814 us; speedup vs baseline: 2.4180x; 1.6287x over previous
//
#include <hip/hip_runtime.h>
#include <cmath>

static constexpr float SCALE_ = 0.17677669529663687f; // 32^-0.5

typedef __attribute__((ext_vector_type(8))) short bf16x8;
typedef __attribute__((ext_vector_type(4))) float f32x4;

__device__ inline ushort bf16h(float f) {
    uint x = __float_as_uint(f);
    return (ushort)((x + 0x7fffu + ((x >> 16) & 1u)) >> 16);
}
__device__ inline float bf16f(ushort u) {
    return __uint_as_float(((uint)u) << 16);
}
// load 8 contiguous floats -> bf16 hi/lo fragments
__device__ inline void cvt8p(const float* p, bf16x8& h8, bf16x8& l8) {
    float4 a = *(const float4*)p;
    float4 b = *(const float4*)(p + 4);
    float f[8] = {a.x, a.y, a.z, a.w, b.x, b.y, b.z, b.w};
    #pragma unroll
    for (int e = 0; e < 8; ++e) {
        ushort hh = bf16h(f[e]);
        ((ushort*)&h8)[e] = hh;
        ((ushort*)&l8)[e] = bf16h(f[e] - bf16f(hh));
    }
}
__device__ inline void cvt8a(const float* f, bf16x8& h8, bf16x8& l8) {
    #pragma unroll
    for (int e = 0; e < 8; ++e) {
        ushort hh = bf16h(f[e]);
        ((ushort*)&h8)[e] = hh;
        ((ushort*)&l8)[e] = bf16h(f[e] - bf16f(hh));
    }
}

// ---------------------------------------------------------------------------
// Small weight-combine GEMM: out[m,n] = scale * sum_k Wa[m,k]*Wb[k,n]
// ---------------------------------------------------------------------------
__global__ __launch_bounds__(256) void smallmm_kernel(
    const float* __restrict__ Wa, const float* __restrict__ Wb,
    const float* __restrict__ scale_p, float* __restrict__ out, int NCb)
{
    int idx = blockIdx.x * 256 + threadIdx.x;
    int n4  = NCb >> 2;
    int m   = idx / n4;
    int n0  = (idx - m * n4) << 2;
    if (m >= 192) return;
    float s = scale_p[0];
    float ax = 0.f, ay = 0.f, az = 0.f, aw = 0.f;
    for (int k = 0; k < 192; ++k) {
        float a = Wa[m * 192 + k];
        const float4 b = *(const float4*)(Wb + (size_t)k * NCb + n0);
        ax += a * b.x; ay += a * b.y; az += a * b.z; aw += a * b.w;
    }
    float4 r = make_float4(ax * s, ay * s, az * s, aw * s);
    *(float4*)(out + (size_t)m * NCb + n0) = r;
}

// ---------------------------------------------------------------------------
// Split-bf16 MFMA GEMM: out = A1@W1 [+ A2@W2] + bias.  (unchanged, verified)
// ---------------------------------------------------------------------------
__global__ __launch_bounds__(256) void gemm_mfma(
    const float* __restrict__ A1, long long a1_bs,
    const float* __restrict__ A2, long long a2_bs,
    const float* __restrict__ W1, const float* __restrict__ W2,
    const float* __restrict__ bias,
    float* __restrict__ out, long long out_bs,
    int NC, int M)
{
    __shared__ __align__(16) ushort Ah[128][40];
    __shared__ __align__(16) ushort Al[128][40];
    __shared__ __align__(16) ushort Bh[64][40];
    __shared__ __align__(16) ushort Bl[64][40];

    const int tid = threadIdx.x;
    const int bm = blockIdx.x, bn = blockIdx.y;

    const int ar  = tid >> 1;
    const int ak0 = (tid & 1) << 4;
    int m_l = bm * 128 + ar;
    if (m_l >= M) m_l = M - 1;
    const int abb = m_l / 49, arr = m_l - abb * 49;
    const float* a1p = A1 + (long long)abb * a1_bs + arr * 192 + ak0;
    const float* a2p = A2 ? (A2 + (long long)abb * a2_bs + arr * 192 + ak0) : nullptr;

    const int wk = tid >> 3;
    const int wf = tid & 7;

    const int lane = tid & 63;
    const int wv = tid >> 6;
    const int wm = (wv >> 1) << 6;
    const int wn = (wv & 1) << 5;
    const int lr = lane & 15;
    const int lg = lane >> 4;

    f32x4 acc[4][2] = {};

    const int nslab = A2 ? 12 : 6;
    for (int slab = 0; slab < nslab; ++slab) {
        const int k6 = (slab < 6) ? slab : slab - 6;
        const float* ap = (slab < 6) ? a1p : a2p;
        const float* Wp = (slab < 6) ? W1 : W2;

        float4 av[4];
        #pragma unroll
        for (int i = 0; i < 4; ++i)
            av[i] = *(const float4*)(ap + k6 * 32 + 4 * i);
        const float* wrow = Wp + (size_t)(k6 * 32 + wk) * NC + bn * 64;
        float4 wv0 = *(const float4*)(wrow + wf * 4);
        float4 wv1 = *(const float4*)(wrow + (wf + 8) * 4);

        __syncthreads();
        #pragma unroll
        for (int i = 0; i < 4; ++i) {
            float fs[4] = {av[i].x, av[i].y, av[i].z, av[i].w};
            ushort4 hq, lq;
            ushort* hp = (ushort*)&hq; ushort* lp = (ushort*)&lq;
            #pragma unroll
            for (int e = 0; e < 4; ++e) {
                ushort hh = bf16h(fs[e]);
                hp[e] = hh;
                lp[e] = bf16h(fs[e] - bf16f(hh));
            }
            *(ushort4*)&Ah[ar][ak0 + 4 * i] = hq;
            *(ushort4*)&Al[ar][ak0 + 4 * i] = lq;
        }
        {
            float f0[4] = {wv0.x, wv0.y, wv0.z, wv0.w};
            float f1[4] = {wv1.x, wv1.y, wv1.z, wv1.w};
            #pragma unroll
            for (int e = 0; e < 4; ++e) {
                int n0 = wf * 4 + e;
                ushort hh = bf16h(f0[e]);
                Bh[n0][wk] = hh;
                Bl[n0][wk] = bf16h(f0[e] - bf16f(hh));
                int n1 = (wf + 8) * 4 + e;
                ushort h2 = bf16h(f1[e]);
                Bh[n1][wk] = h2;
                Bl[n1][wk] = bf16h(f1[e] - bf16f(h2));
            }
        }
        __syncthreads();

        bf16x8 fah[4], fal[4], fbh[2], fbl[2];
        #pragma unroll
        for (int i = 0; i < 4; ++i) {
            fah[i] = *(const bf16x8*)&Ah[wm + 16 * i + lr][8 * lg];
            fal[i] = *(const bf16x8*)&Al[wm + 16 * i + lr][8 * lg];
        }
        #pragma unroll
        for (int j = 0; j < 2; ++j) {
            fbh[j] = *(const bf16x8*)&Bh[wn + 16 * j + lr][8 * lg];
            fbl[j] = *(const bf16x8*)&Bl[wn + 16 * j + lr][8 * lg];
        }
        #pragma unroll
        for (int i = 0; i < 4; ++i)
            #pragma unroll
            for (int j = 0; j < 2; ++j) {
                acc[i][j] = __builtin_amdgcn_mfma_f32_16x16x32_bf16(fah[i], fbh[j], acc[i][j], 0, 0, 0);
                acc[i][j] = __builtin_amdgcn_mfma_f32_16x16x32_bf16(fah[i], fbl[j], acc[i][j], 0, 0, 0);
                acc[i][j] = __builtin_amdgcn_mfma_f32_16x16x32_bf16(fal[i], fbh[j], acc[i][j], 0, 0, 0);
            }
    }

    #pragma unroll
    for (int j = 0; j < 2; ++j) {
        const int col = bn * 64 + wn + 16 * j + lr;
        const float bv = bias ? bias[col] : 0.f;
        #pragma unroll
        for (int i = 0; i < 4; ++i) {
            #pragma unroll
            for (int r = 0; r < 4; ++r) {
                int m = bm * 128 + wm + 16 * i + 4 * lg + r;
                if (m < M) {
                    int b2 = m / 49, r2 = m - b2 * 49;
                    out[(long long)b2 * out_bs + (long long)r2 * NC + col] = acc[i][j][r] + bv;
                }
            }
        }
    }
}

// ---------------------------------------------------------------------------
// MFMA differential attention, one (batch,head) per block, 4 waves.
// Swapped QK^T -> lane-local softmax rows; split-bf16 (3-MFMA) products;
// P redistribution through wave-private LDS (no inter-wave barriers).
// ---------------------------------------------------------------------------
__global__ __launch_bounds__(256, 4) void attn_mfma(
    const float* __restrict__ qT, long long qT_bs, int qT_rs,
    const float* __restrict__ kT, long long kT_bs, int kT_rs,
    const float* __restrict__ vT, long long vT_bs, int vT_rs,
    const float* __restrict__ qR, long long qR_bs, int qR_rs,
    const float* __restrict__ kR, long long kR_bs, int kR_rs,
    const float* __restrict__ vR, long long vR_bs, int vR_rs,
    const float* __restrict__ rpb, const float* __restrict__ lam_ptr,
    float* __restrict__ otm, float* __restrict__ orfm, long long o_bs)
{
    __shared__ __align__(16) ushort Pth[64][72];  // wave-private rows: w*16..w*16+15
    __shared__ __align__(16) ushort Ptl[64][72];
    __shared__ float bias_s[169];

    const int tid = threadIdx.x;
    const int bb = blockIdx.x / 6;
    const int h  = blockIdx.x - bb * 6;
    const int hoff = h * 32;
    const int lane = tid & 63;
    const int w  = tid >> 6;     // wave id = i-tile
    const int li = lane & 15;
    const int lg = lane >> 4;

    for (int idx = tid; idx < 169; idx += 256) bias_s[idx] = rpb[idx * 6 + h];

    float lraw = lam_ptr[0];
    float lam = 1.f / (1.f + __expf(-lraw));
    lam = fminf(fmaxf(lam, 0.01f), 0.99f);

    const int irow = min(w * 16 + li, 48);

    // ---- scores via swapped MFMA: st[s][jt] holds S^T tile (col=i, row=j) ----
    f32x4 st[2][4];
    #pragma unroll
    for (int s = 0; s < 2; ++s) {
        const float* qb = s ? (qR + (long long)bb * qR_bs) : (qT + (long long)bb * qT_bs);
        const int qrs = s ? qR_rs : qT_rs;
        const float* kb = s ? (kR + (long long)bb * kR_bs) : (kT + (long long)bb * kT_bs);
        const int krs = s ? kR_rs : kT_rs;

        bf16x8 qh, ql;
        cvt8p(qb + (long long)irow * qrs + hoff + 8 * lg, qh, ql);
        #pragma unroll
        for (int jt = 0; jt < 4; ++jt) {
            int jr = jt * 16 + li; if (jr > 48) jr = 48;
            bf16x8 kh, kl;
            cvt8p(kb + (long long)jr * krs + hoff + 8 * lg, kh, kl);
            f32x4 c = {};
            c = __builtin_amdgcn_mfma_f32_16x16x32_bf16(kh, qh, c, 0, 0, 0);
            c = __builtin_amdgcn_mfma_f32_16x16x32_bf16(kh, ql, c, 0, 0, 0);
            c = __builtin_amdgcn_mfma_f32_16x16x32_bf16(kl, qh, c, 0, 0, 0);
            st[s][jt] = c;
        }
    }
    __syncthreads();   // bias_s ready (only barrier in the kernel)

    // ---- bias + mask + softmax (row i is lane-local: i = w*16+li) ----
    const int ri = (irow * 9363) >> 16;    // irow / 7
    const int ci = irow - 7 * ri;
    float bias_v[4][4];
    #pragma unroll
    for (int jt = 0; jt < 4; ++jt)
        #pragma unroll
        for (int r = 0; r < 4; ++r) {
            int j = jt * 16 + 4 * lg + r;
            int jc = (j < 49) ? j : 48;
            int rj = (jc * 9363) >> 16;
            int cj = jc - 7 * rj;
            bias_v[jt][r] = bias_s[(ri - rj + 6) * 13 + (ci - cj + 6)];
        }

    float p[2][4][4];
    #pragma unroll
    for (int s = 0; s < 2; ++s) {
        float m = -1e30f;
        #pragma unroll
        for (int jt = 0; jt < 4; ++jt)
            #pragma unroll
            for (int r = 0; r < 4; ++r) {
                int j = jt * 16 + 4 * lg + r;
                float sv = (j < 49) ? (st[s][jt][r] * SCALE_ + bias_v[jt][r]) : -1e30f;
                p[s][jt][r] = sv;
                m = fmaxf(m, sv);
            }
        m = fmaxf(m, __shfl_xor(m, 16));
        m = fmaxf(m, __shfl_xor(m, 32));
        float sum = 0.f;
        #pragma unroll
        for (int jt = 0; jt < 4; ++jt)
            #pragma unroll
            for (int r = 0; r < 4; ++r) {
                float e = __expf(p[s][jt][r] - m);
                p[s][jt][r] = e;
                sum += e;
            }
        sum += __shfl_xor(sum, 16);
        sum += __shfl_xor(sum, 32);
        float inv = 1.f / sum;
        #pragma unroll
        for (int jt = 0; jt < 4; ++jt)
            #pragma unroll
            for (int r = 0; r < 4; ++r)
                p[s][jt][r] *= inv;
    }

    // ---- PV per stream: Peff through wave-private LDS, V direct from global ----
    const int prow = w * 16 + li;
    #pragma unroll
    for (int s = 0; s < 2; ++s) {
        #pragma unroll
        for (int jt = 0; jt < 4; ++jt) {
            ushort4 h4, l4;
            #pragma unroll
            for (int r = 0; r < 4; ++r) {
                float at = p[0][jt][r], ar = p[1][jt][r];
                float f = (s == 0) ? (at - lam * ar) : (ar - lam * at);
                ushort hh = bf16h(f);
                ((ushort*)&h4)[r] = hh;
                ((ushort*)&l4)[r] = bf16h(f - bf16f(hh));
            }
            *(ushort4*)&Pth[prow][jt * 16 + 4 * lg] = h4;
            *(ushort4*)&Ptl[prow][jt * 16 + 4 * lg] = l4;
        }

        const float* vb = s ? (vR + (long long)bb * vR_bs) : (vT + (long long)bb * vT_bs);
        const int vrs = s ? vR_rs : vT_rs;
        f32x4 acc[2] = {};
        #pragma unroll
        for (int ks = 0; ks < 2; ++ks) {
            bf16x8 pah = *(const bf16x8*)&Pth[prow][ks * 32 + 8 * lg];
            bf16x8 pal = *(const bf16x8*)&Ptl[prow][ks * 32 + 8 * lg];
            #pragma unroll
            for (int dt = 0; dt < 2; ++dt) {
                float f[8];
                #pragma unroll
                for (int e = 0; e < 8; ++e) {
                    int j = ks * 32 + 8 * lg + e;
                    f[e] = vb[(long long)j * vrs + hoff + dt * 16 + li];
                }
                bf16x8 vh, vl;
                cvt8a(f, vh, vl);
                acc[dt] = __builtin_amdgcn_mfma_f32_16x16x32_bf16(pah, vh, acc[dt], 0, 0, 0);
                acc[dt] = __builtin_amdgcn_mfma_f32_16x16x32_bf16(pah, vl, acc[dt], 0, 0, 0);
                acc[dt] = __builtin_amdgcn_mfma_f32_16x16x32_bf16(pal, vh, acc[dt], 0, 0, 0);
            }
        }
        float* op = s ? orfm : otm;
        #pragma unroll
        for (int dt = 0; dt < 2; ++dt)
            #pragma unroll
            for (int r = 0; r < 4; ++r) {
                int i = w * 16 + 4 * lg + r;
                if (i < 49)
                    op[(long long)bb * o_bs + (long long)i * 192 + hoff + dt * 16 + li] = acc[dt][r];
            }
    }
}

// ---------------------------------------------------------------------------
extern "C" void kernel_launch(void* const* d_in, const int* in_sizes, int n_in,
                              void* d_out, int out_size, void* d_ws, size_t ws_size,
                              hipStream_t stream)
{
    const float* x_sa      = (const float*)d_in[0];
    const float* x_ca      = (const float*)d_in[1];
    const float* lam_sa    = (const float*)d_in[2];
    const float* lam_ca    = (const float*)d_in[3];
    const float* sa_enh    = (const float*)d_in[4];
    const float* ca_enh    = (const float*)d_in[5];
    const float* W_sa_qkv  = (const float*)d_in[6];
    const float* b_sa_qkv  = (const float*)d_in[7];
    const float* W_sa_ct   = (const float*)d_in[8];
    const float* W_sa_cr   = (const float*)d_in[9];
    const float* W_ca_q    = (const float*)d_in[10];
    const float* b_ca_q    = (const float*)d_in[11];
    const float* W_ca_kv   = (const float*)d_in[12];
    const float* b_ca_kv   = (const float*)d_in[13];
    const float* W_ca_ct   = (const float*)d_in[14];
    const float* W_ca_cr   = (const float*)d_in[15];
    const float* rpb       = (const float*)d_in[16];
    const float* W_proj_sa = (const float*)d_in[17];
    const float* b_proj_sa = (const float*)d_in[18];
    const float* W_proj_ca = (const float*)d_in[19];
    const float* b_proj_ca = (const float*)d_in[20];
    float* out = (float*)d_out;
    float* ws  = (float*)d_ws;

    float* CW0 = ws;
    float* CW1 = CW0 + 110592;
    float* CW2 = CW1 + 110592;
    float* CW3 = CW2 + 36864;
    float* CW4 = CW3 + 36864;
    float* CW5 = CW4 + 73728;
    float* chunkbuf = CW5 + 73728;  // ws + 442368

    smallmm_kernel<<<108, 256, 0, stream>>>(W_sa_cr, W_sa_qkv, sa_enh, CW0, 576);
    smallmm_kernel<<<108, 256, 0, stream>>>(W_sa_ct, W_sa_qkv, sa_enh, CW1, 576);
    smallmm_kernel<<< 36, 256, 0, stream>>>(W_ca_cr, W_ca_q,   ca_enh, CW2, 192);
    smallmm_kernel<<< 36, 256, 0, stream>>>(W_ca_ct, W_ca_q,   ca_enh, CW3, 192);
    smallmm_kernel<<< 72, 256, 0, stream>>>(W_ca_cr, W_ca_kv,  ca_enh, CW4, 384);
    smallmm_kernel<<< 72, 256, 0, stream>>>(W_ca_ct, W_ca_kv,  ca_enh, CW5, 384);

    long long avail = (long long)(ws_size / 4) - 442368;
    int cbmax = (int)(avail / 75264);
    if (cbmax > 2048) cbmax = 2048;
    if (cbmax < 1) cbmax = 1;

    const long long OUT1 = 2LL * 2048 * 49 * 192;
    dim3 blk(256);

    for (int c0 = 0; c0 < 2048; c0 += cbmax) {
        int cb = (c0 + cbmax <= 2048) ? cbmax : (2048 - c0);
        int M = cb * 49;
        int gx = (M + 127) / 128;

        // =========================== SA branch ===========================
        float* qkvt = chunkbuf;
        float* qkvr = qkvt + (long long)cbmax * 28224;
        float* otb  = qkvr + (long long)cbmax * 28224;
        float* orfb = otb  + (long long)cbmax * 9408;

        dim3 g1(gx, 9);
        gemm_mfma<<<g1, blk, 0, stream>>>(
            x_sa + (long long)c0 * 9408, 9408,
            x_sa + (2048LL + c0) * 9408, 9408,
            W_sa_qkv, CW0, b_sa_qkv, qkvt, 28224, 576, M);
        gemm_mfma<<<g1, blk, 0, stream>>>(
            x_sa + (2048LL + c0) * 9408, 9408,
            x_sa + (long long)c0 * 9408, 9408,
            W_sa_qkv, CW1, b_sa_qkv, qkvr, 28224, 576, M);

        attn_mfma<<<cb * 6, blk, 0, stream>>>(
            qkvt,       28224, 576,  qkvt + 192, 28224, 576,  qkvt + 384, 28224, 576,
            qkvr,       28224, 576,  qkvr + 192, 28224, 576,  qkvr + 384, 28224, 576,
            rpb, lam_sa, otb, orfb, 9408);

        dim3 g2(gx, 3);
        gemm_mfma<<<g2, blk, 0, stream>>>(
            otb, 9408, nullptr, 0, W_proj_sa, nullptr, b_proj_sa,
            out + (long long)c0 * 9408, 9408, 192, M);
        gemm_mfma<<<g2, blk, 0, stream>>>(
            orfb, 9408, nullptr, 0, W_proj_sa, nullptr, b_proj_sa,
            out + (2048LL + c0) * 9408, 9408, 192, M);

        // =========================== CA branch ===========================
        float* q_t  = chunkbuf;
        float* q_r  = q_t  + (long long)cbmax * 9408;
        float* kv_t = q_r  + (long long)cbmax * 9408;
        float* kv_r = kv_t + (long long)cbmax * 18816;
        float* otc  = kv_r + (long long)cbmax * 18816;
        float* orfc = otc  + (long long)cbmax * 9408;

        const float* xt_ca = x_ca + (long long)c0 * 18816;
        const float* xr_ca = xt_ca + 9408;

        gemm_mfma<<<g2, blk, 0, stream>>>(
            xt_ca, 18816, xr_ca, 18816, W_ca_q, CW2, b_ca_q, q_t, 9408, 192, M);
        gemm_mfma<<<g2, blk, 0, stream>>>(
            xr_ca, 18816, xt_ca, 18816, W_ca_q, CW3, b_ca_q, q_r, 9408, 192, M);

        dim3 g3(gx, 6);
        gemm_mfma<<<g3, blk, 0, stream>>>(
            xt_ca, 18816, xr_ca, 18816, W_ca_kv, CW4, b_ca_kv, kv_t, 18816, 384, M);
        gemm_mfma<<<g3, blk, 0, stream>>>(
            xr_ca, 18816, xt_ca, 18816, W_ca_kv, CW5, b_ca_kv, kv_r, 18816, 384, M);

        attn_mfma<<<cb * 6, blk, 0, stream>>>(
            q_t,  9408, 192,  kv_t,       18816, 384,  kv_t + 192, 18816, 384,
            q_r,  9408, 192,  kv_r,       18816, 384,  kv_r + 192, 18816, 384,
            rpb, lam_ca, otc, orfc, 9408);

        gemm_mfma<<<g2, blk, 0, stream>>>(
            otc, 9408, nullptr, 0, W_proj_ca, nullptr, b_proj_ca,
            out + OUT1 + (long long)c0 * 18816, 18816, 192, M);
        gemm_mfma<<<g2, blk, 0, stream>>>(
            orfc, 9408, nullptr, 0, W_proj_ca, nullptr, b_proj_ca,
            out + OUT1 + (long long)c0 * 18816 + 9408, 18816, 192, M);
    }
}